// Round 1
// baseline (293.676 us; speedup 1.0000x reference)
//
#include <hip/hip_runtime.h>
#include <stdint.h>

// ---------- problem constants ----------
#define S_LEN   2048
#define D_MODEL 2048
#define NH      32
#define NKV     8
#define HDIM    64
#define WIN     1024
#define QKV_N   3072
#define MTOT    4096          // B*S
#define QSCALE  0.18033688011112042f   // 0.125 * log2(e)

typedef __bf16 bf16x8 __attribute__((ext_vector_type(8)));
typedef float  f32x4  __attribute__((ext_vector_type(4)));
typedef unsigned short u16x8 __attribute__((ext_vector_type(8)));
typedef unsigned short u16x4 __attribute__((ext_vector_type(4)));

#define GLDS16(g, l) __builtin_amdgcn_global_load_lds( \
    (__attribute__((address_space(1))) void*)(g),      \
    (__attribute__((address_space(3))) void*)(l), 16, 0, 0)

__device__ __forceinline__ unsigned short f2bf(float f) {
  union { float f; uint32_t u; } v; v.f = f;
  uint32_t u = v.u;
  u += 0x7fffu + ((u >> 16) & 1u);     // RNE
  return (unsigned short)(u >> 16);
}

// ---------- fp32 -> bf16 conversion (3 segments, vectorized) ----------
__global__ void cvt3(const float* __restrict__ s0, unsigned short* __restrict__ d0, int n0,
                     const float* __restrict__ s1, unsigned short* __restrict__ d1, int n1,
                     const float* __restrict__ s2, unsigned short* __restrict__ d2, int n2)
{
  int total4 = (n0 + n1 + n2) >> 2;
  for (int idx = blockIdx.x * blockDim.x + threadIdx.x; idx < total4;
       idx += gridDim.x * blockDim.x) {
    int i = idx << 2;
    const float* s; unsigned short* d;
    if (i < n0)            { s = s0 + i;            d = d0 + i; }
    else if (i < n0 + n1)  { s = s1 + (i - n0);     d = d1 + (i - n0); }
    else                   { s = s2 + (i - n0 - n1); d = d2 + (i - n0 - n1); }
    float4 v = *(const float4*)s;
    u16x4 o;
    o[0] = f2bf(v.x); o[1] = f2bf(v.y); o[2] = f2bf(v.z); o[3] = f2bf(v.w);
    *(u16x4*)d = o;
  }
}

// ---------- NT GEMM: C[m,n] = sum_k A[m,k]*B[n,k] (+bias) ----------
// m97 structure: 128x128 tile, BK=32, 4 waves (2x2), global_load_lds staging.
// EP==0: QKV epilogue (scatter into Q(scaled)/K/V bf16). EP==1: fp32 out.
template<int EP>
__global__ __launch_bounds__(256)
void gemm_nt(const unsigned short* __restrict__ A, const unsigned short* __restrict__ Bm,
             const float* __restrict__ bias, int K, int N,
             unsigned short* __restrict__ qo, unsigned short* __restrict__ ko,
             unsigned short* __restrict__ vo, float* __restrict__ co)
{
  __shared__ unsigned short sA[128 * 32];
  __shared__ unsigned short sB[128 * 32];
  const int t = threadIdx.x;
  const int l = t & 63;
  const int brow = blockIdx.y << 7;
  const int bcol = blockIdx.x << 7;
  const int wr = ((t >> 7) & 1) << 6;   // wave row half
  const int wc = ((t >> 6) & 1) << 6;   // wave col half

  const int srow  = t >> 2;             // 0..63 staging row
  const int skoff = (t & 3) << 3;       // 0,8,16,24
  const unsigned short* aP = A + (size_t)(brow + srow) * K + skoff;
  const unsigned short* bP = Bm + (size_t)(bcol + srow) * K + skoff;
  unsigned short* ldsA0 = &sA[(t & 192) << 3];
  unsigned short* ldsA1 = &sA[(256 + (t & 192)) << 3];
  unsigned short* ldsB0 = &sB[(t & 192) << 3];
  unsigned short* ldsB1 = &sB[(256 + (t & 192)) << 3];

  f32x4 acc[4][4] = {};
  const int fr = l & 15;
  const int fk = (l >> 4) << 3;

  for (int kt = 0; kt < K; kt += 32) {
    GLDS16(aP, ldsA0);
    GLDS16(aP + (size_t)64 * K, ldsA1);
    GLDS16(bP, ldsB0);
    GLDS16(bP + (size_t)64 * K, ldsB1);
    aP += 32; bP += 32;
    __syncthreads();

    bf16x8 af[4], bf[4];
#pragma unroll
    for (int mi = 0; mi < 4; ++mi)
      af[mi] = *(const bf16x8*)&sA[(wr + mi * 16 + fr) * 32 + fk];
#pragma unroll
    for (int ni = 0; ni < 4; ++ni)
      bf[ni] = *(const bf16x8*)&sB[(wc + ni * 16 + fr) * 32 + fk];
#pragma unroll
    for (int mi = 0; mi < 4; ++mi)
#pragma unroll
      for (int ni = 0; ni < 4; ++ni)
        acc[mi][ni] = __builtin_amdgcn_mfma_f32_16x16x32_bf16(af[mi], bf[ni], acc[mi][ni], 0, 0, 0);
    __syncthreads();
  }

  const int fq4 = (l >> 4) << 2;
  if (EP == 0) {
#pragma unroll
    for (int ni = 0; ni < 4; ++ni) {
      const int e = bcol + wc + ni * 16 + fr;
      const float bs = bias[e];
#pragma unroll
      for (int mi = 0; mi < 4; ++mi) {
#pragma unroll
        for (int j = 0; j < 4; ++j) {
          const int m = brow + wr + mi * 16 + fq4 + j;
          const int b = m >> 11, s = m & 2047;
          float v = acc[mi][ni][j] + bs;
          const int d = e & 63;
          if (e < 2048) {                      // Q, head h = e>>6 (= g*4+r)
            const int h = e >> 6;
            qo[(((size_t)b * NH + h) * S_LEN + s) * HDIM + d] = f2bf(v * QSCALE);
          } else if (e < 2560) {               // K, group g
            const int gg = (e - 2048) >> 6;
            ko[(((size_t)b * NKV + gg) * S_LEN + s) * HDIM + d] = f2bf(v);
          } else {                             // V
            const int gg = (e - 2560) >> 6;
            vo[(((size_t)b * NKV + gg) * S_LEN + s) * HDIM + d] = f2bf(v);
          }
        }
      }
    }
  } else {
#pragma unroll
    for (int mi = 0; mi < 4; ++mi)
#pragma unroll
      for (int j = 0; j < 4; ++j) {
        const int m = brow + wr + mi * 16 + fq4 + j;
#pragma unroll
        for (int ni = 0; ni < 4; ++ni) {
          const int n = bcol + wc + ni * 16 + fr;
          co[(size_t)m * N + n] = acc[mi][ni][j] + bias[n];
        }
      }
  }
}

// ---------- sliding-window flash attention ----------
// grid: (qtile=32, head=32, batch=2); 256 thr = 4 waves x 16 q-rows.
// Q pre-scaled by 0.125*log2(e) -> exp2f softmax.
__global__ __launch_bounds__(256)
void attn_swin(const unsigned short* __restrict__ Qs, const unsigned short* __restrict__ Kb,
               const unsigned short* __restrict__ Vb, unsigned short* __restrict__ ctx)
{
  __shared__ unsigned short sK[64 * 64];    // [key][d], row-XOR-swizzled
  __shared__ unsigned short sVt[64 * 64];   // [d][key], row-XOR-swizzled
  __shared__ unsigned short sP[4][16 * 64]; // per-wave P, row-XOR-swizzled

  const int t = threadIdx.x, w = t >> 6, l = t & 63;
  const int fr = l & 15, fq = l >> 4;
  const int q0 = blockIdx.x << 6;
  const int h = blockIdx.y, b = blockIdx.z;
  const int g = h >> 2;

  // Q fragments (16 rows per wave), direct from global
  const unsigned short* qp = Qs + (((size_t)(b * NH + h)) * S_LEN + q0 + (w << 4)) * HDIM;
  const bf16x8 qf0 = *(const bf16x8*)(qp + fr * 64 + (fq << 3));
  const bf16x8 qf1 = *(const bf16x8*)(qp + fr * 64 + 32 + (fq << 3));

  const unsigned short* Kg = Kb + ((size_t)(b * NKV + g)) * S_LEN * HDIM;
  const unsigned short* Vg = Vb + ((size_t)(b * NKV + g)) * S_LEN * HDIM;

  float m_run[4], l_run[4];
  f32x4 o_acc[4] = {};
#pragma unroll
  for (int r = 0; r < 4; ++r) { m_run[r] = -1e30f; l_run[r] = 0.0f; }

  int lo = q0 - (WIN - 1); if (lo < 0) lo = 0; lo &= ~63;
  const int hi = q0 + 64;

  for (int kv0 = lo; kv0 < hi; kv0 += 64) {
    __syncthreads();   // previous tile's LDS reads complete
    // stage K rows (swizzled b128 writes)
#pragma unroll
    for (int c = 0; c < 2; ++c) {
      const int cn = (c << 8) + t;
      const int key = cn >> 3, dc = cn & 7;
      u16x8 kv = *(const u16x8*)(Kg + (size_t)(kv0 + key) * HDIM + (dc << 3));
      *(u16x8*)((char*)sK + ((((key << 6) + (dc << 3)) << 1) ^ ((key & 7) << 4))) = kv;
    }
    // stage V transposed: wave w covers d-range [w*16, w*16+16) for all 64 keys
    {
      const int key = l, d0 = w << 4;
      u16x8 va = *(const u16x8*)(Vg + (size_t)(kv0 + key) * HDIM + d0);
      u16x8 vb2 = *(const u16x8*)(Vg + (size_t)(kv0 + key) * HDIM + d0 + 8);
#pragma unroll
      for (int jj = 0; jj < 8; ++jj) {
        const int dr = d0 + jj, dr2 = d0 + 8 + jj;
        *(unsigned short*)((char*)sVt + ((((dr << 6) + key) << 1) ^ ((dr & 7) << 4))) = va[jj];
        *(unsigned short*)((char*)sVt + ((((dr2 << 6) + key) << 1) ^ ((dr2 & 7) << 4))) = vb2[jj];
      }
    }
    __syncthreads();

    // S = Q K^T  (S[16q][64keys] as 4 n-tiles)
    f32x4 sf[4];
#pragma unroll
    for (int nt = 0; nt < 4; ++nt) {
      const int key = (nt << 4) + fr;
      const int swz = (key & 7) << 4;
      bf16x8 k0 = *(const bf16x8*)((const char*)sK + ((((key << 6) + (fq << 3)) << 1) ^ swz));
      bf16x8 k1 = *(const bf16x8*)((const char*)sK + ((((key << 6) + 32 + (fq << 3)) << 1) ^ swz));
      f32x4 z = {};
      z = __builtin_amdgcn_mfma_f32_16x16x32_bf16(qf0, k0, z, 0, 0, 0);
      z = __builtin_amdgcn_mfma_f32_16x16x32_bf16(qf1, k1, z, 0, 0, 0);
      sf[nt] = z;
    }
    // mask: valid iff (j <= i) && (j > i - WIN)
#pragma unroll
    for (int nt = 0; nt < 4; ++nt) {
      const int jk = kv0 + (nt << 4) + fr;
#pragma unroll
      for (int r = 0; r < 4; ++r) {
        const int iq = q0 + (w << 4) + (fq << 2) + r;
        if (jk > iq || jk <= iq - WIN) sf[nt][r] = -1e30f;
      }
    }
    // online softmax (wave-parallel row reduce over the 16-lane group)
#pragma unroll
    for (int r = 0; r < 4; ++r) {
      float v = fmaxf(fmaxf(sf[0][r], sf[1][r]), fmaxf(sf[2][r], sf[3][r]));
      v = fmaxf(v, __shfl_xor(v, 1));
      v = fmaxf(v, __shfl_xor(v, 2));
      v = fmaxf(v, __shfl_xor(v, 4));
      v = fmaxf(v, __shfl_xor(v, 8));
      const float mnew = fmaxf(m_run[r], v);
      const float rs = exp2f(m_run[r] - mnew);
      m_run[r] = mnew;
      l_run[r] *= rs;
#pragma unroll
      for (int dt = 0; dt < 4; ++dt) o_acc[dt][r] *= rs;
    }
    float lt[4] = {0.f, 0.f, 0.f, 0.f};
#pragma unroll
    for (int nt = 0; nt < 4; ++nt) {
#pragma unroll
      for (int r = 0; r < 4; ++r) {
        const float p = exp2f(sf[nt][r] - m_run[r]);
        lt[r] += p;
        const int prow = (fq << 2) + r;
        *(unsigned short*)((char*)sP[w] +
            ((((prow << 6) + (nt << 4) + fr) << 1) ^ ((prow & 7) << 4))) = f2bf(p);
      }
    }
#pragma unroll
    for (int r = 0; r < 4; ++r) {
      float v = lt[r];
      v += __shfl_xor(v, 1); v += __shfl_xor(v, 2);
      v += __shfl_xor(v, 4); v += __shfl_xor(v, 8);
      l_run[r] += v;
    }
    // PV: o += P @ V   (same-wave sP round trip, no barrier needed)
#pragma unroll
    for (int ks = 0; ks < 2; ++ks) {
      bf16x8 pf = *(const bf16x8*)((const char*)sP[w] +
          ((((fr << 6) + (ks << 5) + (fq << 3)) << 1) ^ ((fr & 7) << 4)));
#pragma unroll
      for (int dt = 0; dt < 4; ++dt) {
        const int d = (dt << 4) + fr;
        bf16x8 vf = *(const bf16x8*)((const char*)sVt +
            ((((d << 6) + (ks << 5) + (fq << 3)) << 1) ^ ((d & 7) << 4)));
        o_acc[dt] = __builtin_amdgcn_mfma_f32_16x16x32_bf16(pf, vf, o_acc[dt], 0, 0, 0);
      }
    }
  }

  // epilogue: ctx[b][s][h*64+d] bf16
  unsigned short* cp = ctx + ((size_t)(b * S_LEN + q0 + (w << 4))) * D_MODEL + h * HDIM;
#pragma unroll
  for (int r = 0; r < 4; ++r) {
    const float inv = 1.0f / l_run[r];
    const int row = (fq << 2) + r;
#pragma unroll
    for (int dt = 0; dt < 4; ++dt)
      cp[(size_t)row * D_MODEL + (dt << 4) + fr] = f2bf(o_acc[dt][r] * inv);
  }
}

// ---------- launch ----------
extern "C" void kernel_launch(void* const* d_in, const int* in_sizes, int n_in,
                              void* d_out, int out_size, void* d_ws, size_t ws_size,
                              hipStream_t stream)
{
  const float* x    = (const float*)d_in[0];
  const float* Wqkv = (const float*)d_in[1];
  const float* bqkv = (const float*)d_in[2];
  const float* Wout = (const float*)d_in[3];
  const float* bout = (const float*)d_in[4];
  float* out = (float*)d_out;

  char* ws = (char*)d_ws;
  if (ws_size < 62914560u) return;  // need ~60 MiB scratch

  unsigned short* xb    = (unsigned short*)(ws);               // 8M elems (x bf16)
  unsigned short* ctx   = xb;                                  // alias: reused after gemm1
  unsigned short* wqkvb = (unsigned short*)(ws + 16777216);    // 6.29M elems
  unsigned short* woutb = (unsigned short*)(ws + 29360128);    // 4.19M elems
  unsigned short* Qs    = (unsigned short*)(ws + 37748736);    // 8.39M elems (scaled Q)
  unsigned short* Kbuf  = (unsigned short*)(ws + 54525952);    // 2.1M elems
  unsigned short* Vbuf  = (unsigned short*)(ws + 58720256);    // 2.1M elems

  cvt3<<<2048, 256, 0, stream>>>(x, xb, MTOT * D_MODEL,
                                 Wqkv, wqkvb, QKV_N * D_MODEL,
                                 Wout, woutb, D_MODEL * D_MODEL);

  gemm_nt<0><<<dim3(QKV_N / 128, MTOT / 128), 256, 0, stream>>>(
      xb, wqkvb, bqkv, D_MODEL, QKV_N, Qs, Kbuf, Vbuf, nullptr);

  attn_swin<<<dim3(S_LEN / 64, NH, 2), 256, 0, stream>>>(Qs, Kbuf, Vbuf, ctx);

  gemm_nt<1><<<dim3(D_MODEL / 128, MTOT / 128), 256, 0, stream>>>(
      ctx, woutb, bout, D_MODEL, D_MODEL, nullptr, nullptr, nullptr, out);
}